// Round 7
// baseline (754.342 us; speedup 1.0000x reference)
//
#include <hip/hip_runtime.h>
#include <hip/hip_bf16.h>

typedef __bf16 bf16x8_t __attribute__((ext_vector_type(8)));
typedef __bf16 bf16x4_t __attribute__((ext_vector_type(4)));
typedef short s16x4_t  __attribute__((ext_vector_type(4)));
typedef float f32x4_t  __attribute__((ext_vector_type(4)));

#define NB 2
#define NS 2048
#define NHID 3584
#define NHEADS 16
#define NKVH 8
#define DH 256
#define WIN 1024

__device__ __forceinline__ float bf2f(ushort u) {
  union { unsigned v; float f; } x; x.v = ((unsigned)u) << 16; return x.f;
}
__device__ __forceinline__ ushort f2bf(float f) {
  unsigned x = __builtin_bit_cast(unsigned, f);
  unsigned r = (x + 0x7fffu + ((x >> 16) & 1u)) >> 16;
  return (ushort)r;
}

__device__ __forceinline__ void gload16(const void* g, void* l) {
  __builtin_amdgcn_global_load_lds((const __attribute__((address_space(1))) void*)g,
                                   (__attribute__((address_space(3))) void*)l, 16, 0, 0);
}

__device__ __forceinline__ f32x4_t mfma_pv(s16x4_t a, s16x4_t b, f32x4_t c) {
#if __has_builtin(__builtin_amdgcn_mfma_f32_16x16x16_bf16)
  return __builtin_amdgcn_mfma_f32_16x16x16_bf16(
      __builtin_bit_cast(bf16x4_t, a), __builtin_bit_cast(bf16x4_t, b), c, 0, 0, 0);
#else
  return __builtin_amdgcn_mfma_f32_16x16x16bf16_1k(a, b, c, 0, 0, 0);
#endif
}

// p = exp(50*tanh((s/16)/50)) = exp(50*(e^{2x}-1)/(e^{2x}+1)), x = s/800
__device__ __forceinline__ float pexp(float s) {
  float e = __expf(fminf(s * 0.0025f, 60.f));
  float th = __fdividef(e - 1.f, e + 1.f);
  return __expf(50.f * th);
}

// ---------------- f32 -> bf16 elementwise convert (x4 vectorized) ---------
__global__ __launch_bounds__(256) void f32_to_bf16_kernel(const float* __restrict__ in,
                                                          ushort* __restrict__ out, int n4) {
  int i = (int)blockIdx.x * 256 + (int)threadIdx.x;
  if (i < n4) {
    float4 v = ((const float4*)in)[i];
    ushort4 o;
    o.x = f2bf(v.x); o.y = f2bf(v.y); o.z = f2bf(v.z); o.w = f2bf(v.w);
    ((ushort4*)out)[i] = o;
  }
}

// ------------- transpose+convert: f32 in[R][C] -> bf16 out[C][R] ----------
__global__ __launch_bounds__(256) void transpose_f32_bf16(const float* __restrict__ in,
                                                          ushort* __restrict__ out,
                                                          int R, int Cc) {
  __shared__ ushort tile[64][72];
  const int t = threadIdx.x;
  const int ct = Cc >> 6;
  const int by = blockIdx.x / ct;
  const int bx = blockIdx.x % ct;
  const int r0 = by << 6, c0 = bx << 6;
#pragma unroll
  for (int i = 0; i < 16; ++i) {
    int idx = i * 256 + t;
    int r = idx >> 6, c = idx & 63;
    tile[r][c] = f2bf(in[(size_t)(r0 + r) * Cc + c0 + c]);
  }
  __syncthreads();
#pragma unroll
  for (int i = 0; i < 16; ++i) {
    int idx = i * 256 + t;
    int rr = idx >> 6, cc = idx & 63;
    out[(size_t)(c0 + rr) * R + r0 + cc] = tile[cc][rr];
  }
}

// ---------------- GEMM: C[M][N] = A[M][K] * Bt[N][K]^T, bf16 in, f32 acc
// m97 structure: 128x128 tile, BK=64, 4 waves (2x2), global_load_lds width-16
// staging (linear LDS dest, inverse-swizzled global source chunk=(l&7)^(l>>3)),
// swizzled ds_read_b128 (byte ^= (row&7)<<4). Epilogues bounce through LDS and
// issue wide dwordx4 stores.
// EPI=0: bf16 C[row*N+col]. EPI=2: f32 C.
// EPI=4: fused K/V: n0<2048 -> kbuf rows; n0>=2048 -> vtbuf transposed
//        (Cout = kbuf; vtbuf = kbuf + 4096*2048 elements, contiguous in ws).
template <int EPI>
__global__ __launch_bounds__(256, 2) void gemm_bt(const ushort* __restrict__ A,
                                                  const ushort* __restrict__ Bt,
                                                  void* __restrict__ Cout,
                                                  int M, int N, int K) {
  __shared__ alignas(16) char lds[32768];  // lA = lds[0:16K), lB = lds[16K:32K)
  const int t = threadIdx.x;
  const int lane = t & 63;
  const int w = t >> 6;
  const int g = lane >> 4;
  const int lr = lane & 15;
  const int wm = (w >> 1) << 6;
  const int wn = (w & 1) << 6;

  // bijective XCD swizzle (gridDim.x % 8 == 0 for all call sites)
  const int nbn = N >> 7;
  const int nwg = (int)gridDim.x;
  const int bid = (int)blockIdx.x;
  const int swz = (bid & 7) * (nwg >> 3) + (bid >> 3);
  const int bm = swz / nbn, bn = swz % nbn;
  const int m0 = bm << 7, n0 = bn << 7;

  // staging source: wave w stages rows [w*32, w*32+32), 8 rows per issue.
  const int srow = (w << 5) + (lane >> 3);
  const int schunk = (lane & 7) ^ (lane >> 3);
  const ushort* pa = A + (size_t)(m0 + srow) * K + (schunk << 3);
  const ushort* pb = Bt + (size_t)(n0 + srow) * K + (schunk << 3);
  char* ldst = lds + ((w << 5) << 7);  // (w*32)*128 bytes

  f32x4_t acc[4][4] = {};

  const int nkt = K >> 6;
  for (int kt = 0; kt < nkt; ++kt) {
    const int koff = kt << 6;
    __syncthreads();  // previous tile's reads complete before overwrite
#pragma unroll
    for (int j = 0; j < 4; ++j) {
      gload16(pa + (size_t)(j << 3) * K + koff, ldst + (j << 10));
      gload16(pb + (size_t)(j << 3) * K + koff, ldst + 16384 + (j << 10));
    }
    __syncthreads();  // compiler drains vmcnt(0) before s_barrier
#pragma unroll
    for (int ks = 0; ks < 2; ++ks) {
      bf16x8_t af[4], bfv[4];
#pragma unroll
      for (int mi = 0; mi < 4; ++mi) {
        int row = wm + (mi << 4) + lr;
        af[mi] = *(const bf16x8_t*)(lds + (((row << 7) + (ks << 6) + (g << 4)) ^ ((row & 7) << 4)));
      }
#pragma unroll
      for (int nj = 0; nj < 4; ++nj) {
        int row = wn + (nj << 4) + lr;
        bfv[nj] = *(const bf16x8_t*)(lds + 16384 + (((row << 7) + (ks << 6) + (g << 4)) ^ ((row & 7) << 4)));
      }
#pragma unroll
      for (int mi = 0; mi < 4; ++mi)
#pragma unroll
        for (int nj = 0; nj < 4; ++nj)
          acc[mi][nj] = __builtin_amdgcn_mfma_f32_16x16x32_bf16(af[mi], bfv[nj], acc[mi][nj], 0, 0, 0);
    }
  }

  // ---- epilogue: stage whole 128x128 bf16 tile in LDS, then wide stores ----
  const bool trstage = (EPI == 4) && (n0 >= 2048);
  __syncthreads();
  if (trstage) {
    // stage TRANSPOSED: lds[col][row]
#pragma unroll
    for (int mi = 0; mi < 4; ++mi)
#pragma unroll
      for (int nj = 0; nj < 4; ++nj) {
        int col = wn + (nj << 4) + lr;
#pragma unroll
        for (int r = 0; r < 4; ++r) {
          int row = wm + (mi << 4) + (g << 2) + r;
          *(ushort*)(lds + (((col << 8) + (row << 1)) ^ ((col & 7) << 4))) = f2bf(acc[mi][nj][r]);
        }
      }
  } else {
#pragma unroll
    for (int mi = 0; mi < 4; ++mi)
#pragma unroll
      for (int nj = 0; nj < 4; ++nj) {
        int col = wn + (nj << 4) + lr;
#pragma unroll
        for (int r = 0; r < 4; ++r) {
          int row = wm + (mi << 4) + (g << 2) + r;
          *(ushort*)(lds + (((row << 8) + (col << 1)) ^ ((row & 7) << 4))) = f2bf(acc[mi][nj][r]);
        }
      }
  }
  __syncthreads();

  if (EPI == 0) {
    ushort* C = (ushort*)Cout;
#pragma unroll
    for (int it = 0; it < 8; ++it) {
      int idx = it * 256 + t;
      int row = idx >> 4, ch = idx & 15;
      uint4 v = *(const uint4*)(lds + (((row << 8) + (ch << 4)) ^ ((row & 7) << 4)));
      *(uint4*)(C + (size_t)(m0 + row) * N + n0 + (ch << 3)) = v;
    }
  } else if (EPI == 4) {
    ushort* C = (ushort*)Cout;
    if (n0 < 2048) {  // K half -> kbuf [4096][2048]
#pragma unroll
      for (int it = 0; it < 8; ++it) {
        int idx = it * 256 + t;
        int row = idx >> 4, ch = idx & 15;
        uint4 v = *(const uint4*)(lds + (((row << 8) + (ch << 4)) ^ ((row & 7) << 4)));
        *(uint4*)(C + (size_t)(m0 + row) * 2048 + n0 + (ch << 3)) = v;
      }
    } else {  // V half -> vtbuf [(b*8+kvh)*256+d][NS], transposed
      ushort* vC = C + (size_t)4096 * 2048;
      const int bb = m0 >> 11;
      const int ss = m0 & (NS - 1);
#pragma unroll
      for (int it = 0; it < 8; ++it) {
        int idx = it * 256 + t;
        int dc = idx >> 4, ch = idx & 15;
        uint4 v = *(const uint4*)(lds + (((dc << 8) + (ch << 4)) ^ ((dc & 7) << 4)));
        int gc = (n0 - 2048) + dc;
        int kvh = gc >> 8, d = gc & 255;
        *(uint4*)(vC + ((size_t)((bb * NKVH + kvh) * DH + d)) * NS + ss + (ch << 3)) = v;
      }
    }
  } else {
    float* Cf = (float*)Cout;
#pragma unroll
    for (int it = 0; it < 16; ++it) {
      int idx = it * 256 + t;
      int row = idx >> 5, qd = idx & 31;
      ushort4 hv = *(const ushort4*)(lds + (((row << 8) + (qd << 3)) ^ ((row & 7) << 4)));
      float4 fv;
      fv.x = bf2f(hv.x); fv.y = bf2f(hv.y); fv.z = bf2f(hv.z); fv.w = bf2f(hv.w);
      *(float4*)(Cf + (size_t)(m0 + row) * N + n0 + (qd << 2)) = fv;
    }
  }
}

// ---------------- RoPE in-place on bf16 [B*S][nheads*256], pairs (d,d+128) -
__global__ __launch_bounds__(256) void rope_kernel(ushort* __restrict__ buf,
                                                   const float* __restrict__ sint,
                                                   const float* __restrict__ cost,
                                                   int nheads) {
  int idx = (int)blockIdx.x * 256 + (int)threadIdx.x;
  int d = idx & 127;
  int h = (idx >> 7) % nheads;
  int tok = idx / (nheads << 7);
  int pos = tok & (NS - 1);
  float c = cost[pos * DH + d];
  float s = sint[pos * DH + d];
  size_t base = (size_t)tok * ((size_t)nheads * DH) + h * DH + d;
  float x1 = bf2f(buf[base]);
  float x2 = bf2f(buf[base + 128]);
  buf[base] = f2bf(x1 * c - x2 * s);
  buf[base + 128] = f2bf(x2 * c + x1 * s);
}

// ---------------- flash attention, sliding window + softcap ----------------
// grid: B*NKVH*(S/64) = 512; block 256 = 4 waves, each wave 16 q-rows.
// TWO heads per block (h0=2*kvh, h0+1): K and V tiles shared, staging/barriers
// amortized over 2x MFMA, K/V HBM traffic halved.
// Swapped QK^T: S^T = mfma(K, Q). Fixed-max softmax (softcap bounds |logit|<=50).
// K LDS: [32 keys][256 d] rows 512B, 16B-chunk XOR swz (row&7).
// V LDS: d-pair rows [128 r=d>>1][2][32 keys] rows 128B, chunk XOR swz (r&7)
//        -> 2-way (free) bank access on PV ds_read_b64 (fixes round-6 4-way).
__global__ __launch_bounds__(256) void attn_kernel(const ushort* __restrict__ q,
                                                   const ushort* __restrict__ k,
                                                   const ushort* __restrict__ vt,
                                                   ushort* __restrict__ ao) {
  __shared__ alignas(16) char lK[2][16384];
  __shared__ alignas(16) char lV[2][16384];
  const int bid = (int)blockIdx.x;
  const int qb = bid & 31;
  const int kvh = (bid >> 5) & 7;
  const int b = bid >> 8;
  const int h0 = kvh << 1;
  const int qb0 = qb << 6;
  const int t = threadIdx.x;
  const int lane = t & 63;
  const int w = t >> 6;
  const int g = lane >> 4;
  const int lr = lane & 15;

  const int qrow = qb0 + (w << 4) + lr;  // this lane's query (B-operand col)
  bf16x8_t qf0[8], qf1[8];
  const ushort* qbase = q + (size_t)(b * NS + qrow) * (NHEADS * DH) + h0 * DH;
#pragma unroll
  for (int ks = 0; ks < 8; ++ks) {
    qf0[ks] = *(const bf16x8_t*)(qbase + (ks << 5) + (g << 3));
    qf1[ks] = *(const bf16x8_t*)(qbase + DH + (ks << 5) + (g << 3));
  }

  float l0 = 0.f, l1 = 0.f;
  f32x4_t oacc0[16] = {}, oacc1[16] = {};

  const int qminw = qb0 + (w << 4);
  const int qmaxw = qminw + 15;
  int t_lo = qb0 - (WIN - 1);
  if (t_lo < 0) t_lo = 0;
  t_lo &= ~31;
  const int t_hi = qb0 + 63;

  const ushort* kgb = k + (size_t)(b * NS) * (NKVH * DH) + kvh * DH;
  const ushort* vgb = vt + (size_t)((b * NKVH + kvh) * DH) * NS;

  auto stage = [&](int kt, int bi) {
    char* dk = lK[bi];
    char* dv = lV[bi];
#pragma unroll
    for (int j = 0; j < 4; ++j) {
      // K: wave w stages rows w*8..w*8+7; 2 rows (1KB) per issue.
      int row = (w << 3) + (j << 1) + (lane >> 5);
      int ck = (lane & 31) ^ (row & 7);
      gload16(kgb + (size_t)(kt + row) * (NKVH * DH) + (ck << 3),
              dk + (((w << 3) + (j << 1)) << 9));
      // V: d-pair rows. wave w stages rows w*32+j*8 .. +7 (1KB per issue).
      // lane i: r = base + (i>>3), phys chunk p=i&7 holds logical lp=p^(i>>3):
      //   d = 2r + (lp>>2), key-chunk = (lp&3)*8.
      int rv = (w << 5) + (j << 3) + (lane >> 3);
      int lp = (lane & 7) ^ (lane >> 3);
      int dsrc = (rv << 1) + (lp >> 2);
      gload16(vgb + (size_t)dsrc * NS + kt + ((lp & 3) << 3),
              dv + (((w << 5) + (j << 3)) << 7));
    }
  };

  int cur = 0;
  stage(t_lo, 0);
  __syncthreads();

  for (int kt = t_lo; kt <= t_hi; kt += 32) {
    if (kt + 32 <= t_hi) stage(kt + 32, cur ^ 1);  // async prefetch
    const char* lk = lK[cur];
    const char* lv = lV[cur];
#pragma unroll
    for (int sub = 0; sub < 2; ++sub) {
      const int key0 = kt + (sub << 4);
      if (key0 > qmaxw) continue;                    // fully above causal for wave
      if (key0 + 15 < qminw - (WIN - 1)) continue;   // fully below window for wave

      f32x4_t s0 = {}, s1 = {};
      __builtin_amdgcn_s_setprio(1);
#pragma unroll
      for (int ks = 0; ks < 8; ++ks) {
        int row = (sub << 4) + lr;
        bf16x8_t kf = *(const bf16x8_t*)(lk + (((row << 9) + (ks << 6) + (g << 4)) ^ ((row & 7) << 4)));
        s0 = __builtin_amdgcn_mfma_f32_16x16x32_bf16(kf, qf0[ks], s0, 0, 0, 0);
        s1 = __builtin_amdgcn_mfma_f32_16x16x32_bf16(kf, qf1[ks], s1, 0, 0, 0);
      }
      __builtin_amdgcn_s_setprio(0);

      float p0[4], p1[4];
      const bool full = (key0 + 15 <= qminw) && (key0 >= qmaxw - (WIN - 1));
      if (full) {  // wave-uniform: no mask VALU
#pragma unroll
        for (int r = 0; r < 4; ++r) {
          p0[r] = pexp(s0[r]); l0 += p0[r];
          p1[r] = pexp(s1[r]); l1 += p1[r];
        }
      } else {
#pragma unroll
        for (int r = 0; r < 4; ++r) {
          int key = key0 + (g << 2) + r;
          bool ok = (key <= qrow) && (qrow - key < WIN);
          p0[r] = ok ? pexp(s0[r]) : 0.f; l0 += p0[r];
          p1[r] = ok ? pexp(s1[r]) : 0.f; l1 += p1[r];
        }
      }

      s16x4_t pa0, pa1;
#pragma unroll
      for (int r = 0; r < 4; ++r) {
        pa0[r] = (short)f2bf(p0[r]);
        pa1[r] = (short)f2bf(p1[r]);
      }

      __builtin_amdgcn_s_setprio(1);
#pragma unroll
      for (int dt = 0; dt < 16; ++dt) {
        int d = (dt << 4) + lr;
        int rv = d >> 1;
        int off = (rv << 7) + ((((d & 1) << 6) + (sub << 5) + (g << 3)) ^ ((rv & 7) << 4));
        s16x4_t vf = *(const s16x4_t*)(lv + off);
        oacc0[dt] = mfma_pv(pa0, vf, oacc0[dt]);
        oacc1[dt] = mfma_pv(pa1, vf, oacc1[dt]);
      }
      __builtin_amdgcn_s_setprio(0);
    }
    __syncthreads();  // drains vmcnt: prefetched tile ready; buffers safe
    cur ^= 1;
  }

  // deferred l reduction: sum the 4 lane-groups, then broadcast per q-row
  l0 += __shfl_xor(l0, 16); l0 += __shfl_xor(l0, 32);
  l1 += __shfl_xor(l1, 16); l1 += __shfl_xor(l1, 32);
  float dn0[4], dn1[4];
#pragma unroll
  for (int r = 0; r < 4; ++r) {
    dn0[r] = 1.0f / __shfl(l0, (g << 2) + r);
    dn1[r] = 1.0f / __shfl(l1, (g << 2) + r);
  }

  const int orow0 = b * NS + qb0 + (w << 4) + (g << 2);
#pragma unroll
  for (int dt = 0; dt < 16; ++dt) {
    int col = h0 * DH + (dt << 4) + lr;
#pragma unroll
    for (int r = 0; r < 4; ++r) {
      ao[(size_t)(orow0 + r) * (NHEADS * DH) + col] = f2bf(oacc0[dt][r] * dn0[r]);
      ao[(size_t)(orow0 + r) * (NHEADS * DH) + col + DH] = f2bf(oacc1[dt][r] * dn1[r]);
    }
  }
}

extern "C" void kernel_launch(void* const* d_in, const int* in_sizes, int n_in,
                              void* d_out, int out_size, void* d_ws, size_t ws_size,
                              hipStream_t stream) {
  const float* hs   = (const float*)d_in[0];
  const float* sint = (const float*)d_in[3];
  const float* cost = (const float*)d_in[4];
  const float* Wq = (const float*)d_in[6];
  const float* Wk = (const float*)d_in[7];
  const float* Wv = (const float*)d_in[8];
  const float* Wo = (const float*)d_in[9];

  char* ws = (char*)d_ws;
  size_t off = 0;
  auto alloc = [&](size_t bytes) {
    char* p = ws + off;
    off += (bytes + 255) & ~(size_t)255;
    return p;
  };
  ushort* hsb   = (ushort*)alloc((size_t)4096 * 3584 * 2);  // hs in bf16
  ushort* wT    = (ushort*)alloc((size_t)4096 * 3584 * 2);  // reused weight^T buffer
  ushort* qbuf  = (ushort*)alloc((size_t)4096 * 4096 * 2);
  ushort* kbuf  = (ushort*)alloc((size_t)4096 * 2048 * 2);  // MUST precede vtbuf
  ushort* vtbuf = (ushort*)alloc((size_t)4096 * 2048 * 2);  // = kbuf + 4096*2048
  ushort* aobuf = qbuf;  // alias: attn writes exactly the region only it reads
  if (off > ws_size) return;  // ws too small: leaves output zeroed (visible failure)

  // hs f32 -> bf16
  f32_to_bf16_kernel<<<(4096 * 3584 / 4) / 256, 256, 0, stream>>>(hs, hsb, 4096 * 3584 / 4);

  // fused K+V projection: Bt = [WkT; WvT] stacked in wT (rows 0..2047 / 2048..4095)
  transpose_f32_bf16<<<(3584 / 64) * (2048 / 64), 256, 0, stream>>>(Wk, wT, 3584, 2048);
  transpose_f32_bf16<<<(3584 / 64) * (2048 / 64), 256, 0, stream>>>(Wv, wT + (size_t)2048 * 3584, 3584, 2048);
  gemm_bt<4><<<32 * 32, 256, 0, stream>>>(hsb, wT, kbuf, 4096, 4096, 3584);

  // Q projection
  transpose_f32_bf16<<<(3584 / 64) * (4096 / 64), 256, 0, stream>>>(Wq, wT, 3584, 4096);
  gemm_bt<0><<<32 * 32, 256, 0, stream>>>(hsb, wT, qbuf, 4096, 4096, 3584);

  // RoPE (q then k), in-place
  rope_kernel<<<(4096 * 16 * 128) / 256, 256, 0, stream>>>(qbuf, sint, cost, 16);
  rope_kernel<<<(4096 * 8 * 128) / 256, 256, 0, stream>>>(kbuf, sint, cost, 8);

  // attention: 2 heads per block (ao aliases qbuf)
  attn_kernel<<<NB * NKVH * (NS / 64), 256, 0, stream>>>(qbuf, kbuf, vtbuf, aobuf);

  // output projection, f32 out
  transpose_f32_bf16<<<(4096 / 64) * (3584 / 64), 256, 0, stream>>>(Wo, wT, 4096, 3584);
  gemm_bt<2><<<32 * 28, 256, 0, stream>>>(aobuf, wT, d_out, 4096, 3584, 4096);
}

// Round 8
// 604.247 us; speedup vs baseline: 1.2484x; 1.2484x over previous
//
#include <hip/hip_runtime.h>
#include <hip/hip_bf16.h>

typedef __bf16 bf16x8_t __attribute__((ext_vector_type(8)));
typedef __bf16 bf16x4_t __attribute__((ext_vector_type(4)));
typedef short s16x4_t  __attribute__((ext_vector_type(4)));
typedef float f32x4_t  __attribute__((ext_vector_type(4)));

#define NB 2
#define NS 2048
#define NHID 3584
#define NHEADS 16
#define NKVH 8
#define DH 256
#define WIN 1024

__device__ __forceinline__ float bf2f(ushort u) {
  union { unsigned v; float f; } x; x.v = ((unsigned)u) << 16; return x.f;
}
__device__ __forceinline__ ushort f2bf(float f) {
  unsigned x = __builtin_bit_cast(unsigned, f);
  unsigned r = (x + 0x7fffu + ((x >> 16) & 1u)) >> 16;
  return (ushort)r;
}

__device__ __forceinline__ void gload16(const void* g, void* l) {
  __builtin_amdgcn_global_load_lds((const __attribute__((address_space(1))) void*)g,
                                   (__attribute__((address_space(3))) void*)l, 16, 0, 0);
}

__device__ __forceinline__ f32x4_t mfma_pv(s16x4_t a, s16x4_t b, f32x4_t c) {
#if __has_builtin(__builtin_amdgcn_mfma_f32_16x16x16_bf16)
  return __builtin_amdgcn_mfma_f32_16x16x16_bf16(
      __builtin_bit_cast(bf16x4_t, a), __builtin_bit_cast(bf16x4_t, b), c, 0, 0, 0);
#else
  return __builtin_amdgcn_mfma_f32_16x16x16bf16_1k(a, b, c, 0, 0, 0);
#endif
}

// p = exp(50*tanh((s/16)/50)); x = s/800; bounded by e^50 (fixed-max softmax safe)
__device__ __forceinline__ float pexp(float s) {
  float e = __expf(fminf(s * 0.0025f, 80.f));
  float th = __fdividef(e - 1.f, e + 1.f);
  return __expf(50.f * th);
}

// ---------------- f32 -> bf16 elementwise convert (x4 vectorized) ---------
__global__ __launch_bounds__(256) void f32_to_bf16_kernel(const float* __restrict__ in,
                                                          ushort* __restrict__ out, int n4) {
  int i = (int)blockIdx.x * 256 + (int)threadIdx.x;
  if (i < n4) {
    float4 v = ((const float4*)in)[i];
    ushort4 o;
    o.x = f2bf(v.x); o.y = f2bf(v.y); o.z = f2bf(v.z); o.w = f2bf(v.w);
    ((ushort4*)out)[i] = o;
  }
}

// ------------- transpose+convert: f32 in[R][C] -> bf16 out[C][R] ----------
__global__ __launch_bounds__(256) void transpose_f32_bf16(const float* __restrict__ in,
                                                          ushort* __restrict__ out,
                                                          int R, int Cc) {
  __shared__ ushort tile[64][72];
  const int t = threadIdx.x;
  const int ct = Cc >> 6;
  const int by = blockIdx.x / ct;
  const int bx = blockIdx.x % ct;
  const int r0 = by << 6, c0 = bx << 6;
#pragma unroll
  for (int i = 0; i < 16; ++i) {
    int idx = i * 256 + t;
    int r = idx >> 6, c = idx & 63;
    tile[r][c] = f2bf(in[(size_t)(r0 + r) * Cc + c0 + c]);
  }
  __syncthreads();
#pragma unroll
  for (int i = 0; i < 16; ++i) {
    int idx = i * 256 + t;
    int rr = idx >> 6, cc = idx & 63;
    out[(size_t)(c0 + rr) * R + r0 + cc] = tile[cc][rr];
  }
}

// ============ 8-phase 256x256 GEMM: C = A[M][K] * Bt[N][K]^T ==============
// 512 thr = 8 waves (2M x 4N); BK=64; LDS 128KB = 2dbuf x (A 32K + B 32K).
// Per K-tile: 4 phases (mi-half x ks). Per phase: ds-reads, 2 quarter stages
// (tile t+1 -> other buf), raw barrier, lgkmcnt(0), 16 MFMA (setprio), counted
// vmcnt(2), raw barrier. Stage->consume gap >= 2 phases by construction.
// Swizzle: 128B rows, byte ^= (row&7)<<4; gload source pre-swizzled (rule 21).
// EPI=0: bf16 C[M][N]. EPI=2: f32 C. EPI=4: fused KV (K rows / V transposed).
#define GSYNC1 do { __builtin_amdgcn_s_barrier(); \
    asm volatile("s_waitcnt lgkmcnt(0)" ::: "memory"); \
    __builtin_amdgcn_sched_barrier(0); } while (0)
#define GSYNC2(st) do { \
    if (st) asm volatile("s_waitcnt vmcnt(2)" ::: "memory"); \
    else    asm volatile("s_waitcnt vmcnt(0)" ::: "memory"); \
    __builtin_amdgcn_sched_barrier(0); \
    __builtin_amdgcn_s_barrier(); } while (0)

template <int EPI>
__global__ __launch_bounds__(512, 2) void gemm256(const ushort* __restrict__ A,
                                                  const ushort* __restrict__ Bt,
                                                  void* __restrict__ Cout,
                                                  int M, int N, int K) {
  __shared__ alignas(16) char lds[131072];
  const int t = threadIdx.x;
  const int lane = t & 63;
  const int wid = t >> 6;
  const int wm = wid >> 2;   // 0..1
  const int wn = wid & 3;    // 0..3
  const int g = lane >> 4;
  const int lr = lane & 15;
  const int lrow8 = lane >> 3;
  const int lp = (lane & 7) ^ lrow8;  // pre-swizzled staging chunk

  const int nbn = N >> 8;
  const int nwg = (int)gridDim.x;
  const int bid = (int)blockIdx.x;
  const int swz = (bid & 7) * (nwg >> 3) + (bid >> 3);
  const int bm = swz / nbn, bn = swz % nbn;
  const int m0 = bm << 8, n0 = bn << 8;

  f32x4_t acc[8][4] = {};
  const int T = K >> 6;

  auto stageA = [&](int q, int koff, int bufn) {
    int row = (q << 6) + (wid << 3) + lrow8;
    gload16(A + (size_t)(m0 + row) * K + koff + (lp << 3),
            lds + bufn * 32768 + (q << 13) + (wid << 10));
  };
  auto stageB = [&](int q, int koff, int bufn) {
    int row = (q << 6) + (wid << 3) + lrow8;
    gload16(Bt + (size_t)(n0 + row) * K + koff + (lp << 3),
            lds + 65536 + bufn * 32768 + (q << 13) + (wid << 10));
  };

  // prologue: tile 0 -> buf 0 (full drain OK here)
#pragma unroll
  for (int q = 0; q < 4; ++q) { stageA(q, 0, 0); stageB(q, 0, 0); }
  asm volatile("s_waitcnt vmcnt(0)" ::: "memory");
  __builtin_amdgcn_s_barrier();

  for (int tt = 0; tt < T; ++tt) {
    const int bc = tt & 1;
    const int bnx = bc ^ 1;
    const bool st = (tt + 1 < T);
    const int kn = (tt + 1) << 6;
    const char* cA = lds + bc * 32768;
    const char* cB = lds + 65536 + bc * 32768;
    bf16x8_t af[4], bfv[4];

    auto ldA = [&](int i, int mh, int ks) {
      int row = (wm << 7) + (mh << 6) + (i << 4) + lr;
      af[i] = *(const bf16x8_t*)(cA + (row << 7) + (((ks << 6) + (g << 4)) ^ ((row & 7) << 4)));
    };
    auto ldB = [&](int j, int ks) {
      int row = (wn << 6) + (j << 4) + lr;
      bfv[j] = *(const bf16x8_t*)(cB + (row << 7) + (((ks << 6) + (g << 4)) ^ ((row & 7) << 4)));
    };

    // ---- phase 0: mh0, ks0 ----
#pragma unroll
    for (int i = 0; i < 4; ++i) ldA(i, 0, 0);
#pragma unroll
    for (int j = 0; j < 4; ++j) ldB(j, 0);
    if (st) { stageA(0, kn, bnx); stageA(2, kn, bnx); }
    GSYNC1;
    __builtin_amdgcn_s_setprio(1);
#pragma unroll
    for (int i = 0; i < 4; ++i)
#pragma unroll
      for (int j = 0; j < 4; ++j)
        acc[i][j] = __builtin_amdgcn_mfma_f32_16x16x32_bf16(af[i], bfv[j], acc[i][j], 0, 0, 0);
    __builtin_amdgcn_s_setprio(0);
    GSYNC2(st);

    // ---- phase 1: mh1, ks0 (B reused in regs) ----
#pragma unroll
    for (int i = 0; i < 4; ++i) ldA(i, 1, 0);
    if (st) { stageB(0, kn, bnx); stageB(1, kn, bnx); }
    GSYNC1;
    __builtin_amdgcn_s_setprio(1);
#pragma unroll
    for (int i = 0; i < 4; ++i)
#pragma unroll
      for (int j = 0; j < 4; ++j)
        acc[4 + i][j] = __builtin_amdgcn_mfma_f32_16x16x32_bf16(af[i], bfv[j], acc[4 + i][j], 0, 0, 0);
    __builtin_amdgcn_s_setprio(0);
    GSYNC2(st);

    // ---- phase 2: mh0, ks1 ----
#pragma unroll
    for (int i = 0; i < 4; ++i) ldA(i, 0, 1);
#pragma unroll
    for (int j = 0; j < 4; ++j) ldB(j, 1);
    if (st) { stageB(2, kn, bnx); stageB(3, kn, bnx); }
    GSYNC1;
    __builtin_amdgcn_s_setprio(1);
#pragma unroll
    for (int i = 0; i < 4; ++i)
#pragma unroll
      for (int j = 0; j < 4; ++j)
        acc[i][j] = __builtin_amdgcn_mfma_f32_16x16x32_bf16(af[i], bfv[j], acc[i][j], 0, 0, 0);
    __builtin_amdgcn_s_setprio(0);
    GSYNC2(st);

    // ---- phase 3: mh1, ks1 ----
#pragma unroll
    for (int i = 0; i < 4; ++i) ldA(i, 1, 1);
    if (st) { stageA(1, kn, bnx); stageA(3, kn, bnx); }
    GSYNC1;
    __builtin_amdgcn_s_setprio(1);
#pragma unroll
    for (int i = 0; i < 4; ++i)
#pragma unroll
      for (int j = 0; j < 4; ++j)
        acc[4 + i][j] = __builtin_amdgcn_mfma_f32_16x16x32_bf16(af[i], bfv[j], acc[4 + i][j], 0, 0, 0);
    __builtin_amdgcn_s_setprio(0);
    GSYNC2(st);
  }

  // ---- epilogue: bounce 256x256 bf16 tile through LDS, wide stores ----
  __syncthreads();
  const bool trstage = (EPI == 4) && (n0 >= 2048);
  if (trstage) {
#pragma unroll
    for (int i = 0; i < 8; ++i)
#pragma unroll
      for (int j = 0; j < 4; ++j) {
        int col = (wn << 6) + (j << 4) + lr;
#pragma unroll
        for (int r = 0; r < 4; ++r) {
          int row = (wm << 7) + (i << 4) + (g << 2) + r;
          *(ushort*)(lds + (col << 9) + ((row << 1) ^ ((col & 7) << 4))) = f2bf(acc[i][j][r]);
        }
      }
  } else {
#pragma unroll
    for (int i = 0; i < 8; ++i)
#pragma unroll
      for (int j = 0; j < 4; ++j) {
        int col = (wn << 6) + (j << 4) + lr;
#pragma unroll
        for (int r = 0; r < 4; ++r) {
          int row = (wm << 7) + (i << 4) + (g << 2) + r;
          *(ushort*)(lds + (row << 9) + ((col << 1) ^ ((row & 7) << 4))) = f2bf(acc[i][j][r]);
        }
      }
  }
  __syncthreads();

  if (EPI == 0) {
    ushort* C = (ushort*)Cout;
#pragma unroll
    for (int it = 0; it < 16; ++it) {
      int idx = it * 512 + t;
      int row = idx >> 5, ch = idx & 31;
      uint4 v = *(const uint4*)(lds + (row << 9) + ((ch << 4) ^ ((row & 7) << 4)));
      *(uint4*)(C + (size_t)(m0 + row) * N + n0 + (ch << 3)) = v;
    }
  } else if (EPI == 4) {
    ushort* C = (ushort*)Cout;
    if (n0 < 2048) {  // K half -> kbuf [4096][2048]
#pragma unroll
      for (int it = 0; it < 16; ++it) {
        int idx = it * 512 + t;
        int row = idx >> 5, ch = idx & 31;
        uint4 v = *(const uint4*)(lds + (row << 9) + ((ch << 4) ^ ((row & 7) << 4)));
        *(uint4*)(C + (size_t)(m0 + row) * 2048 + n0 + (ch << 3)) = v;
      }
    } else {  // V half -> vtbuf [(b*8+kvh)*256+d][NS], transposed
      ushort* vC = C + (size_t)4096 * 2048;
      const int bb = m0 >> 11;
      const int ss = m0 & (NS - 1);
#pragma unroll
      for (int it = 0; it < 16; ++it) {
        int idx = it * 512 + t;
        int dc = idx >> 5, ch = idx & 31;
        uint4 v = *(const uint4*)(lds + (dc << 9) + ((ch << 4) ^ ((dc & 7) << 4)));
        int gc = (n0 - 2048) + dc;
        int kvh = gc >> 8, d = gc & 255;
        *(uint4*)(vC + ((size_t)((bb * NKVH + kvh) * DH + d)) * NS + ss + (ch << 3)) = v;
      }
    }
  } else {
    float* Cf = (float*)Cout;
#pragma unroll
    for (int it = 0; it < 32; ++it) {
      int idx = it * 512 + t;
      int row = idx >> 6, qd = idx & 63;
      ushort4 hv = *(const ushort4*)(lds + (row << 9) + ((qd << 3) ^ ((row & 7) << 4)));
      float4 fv;
      fv.x = bf2f(hv.x); fv.y = bf2f(hv.y); fv.z = bf2f(hv.z); fv.w = bf2f(hv.w);
      *(float4*)(Cf + (size_t)(m0 + row) * N + n0 + (qd << 2)) = fv;
    }
  }
}

// ---------------- RoPE in-place on bf16 [B*S][nheads*256], pairs (d,d+128) -
__global__ __launch_bounds__(256) void rope_kernel(ushort* __restrict__ buf,
                                                   const float* __restrict__ sint,
                                                   const float* __restrict__ cost,
                                                   int nheads) {
  int idx = (int)blockIdx.x * 256 + (int)threadIdx.x;
  int d = idx & 127;
  int h = (idx >> 7) % nheads;
  int tok = idx / (nheads << 7);
  int pos = tok & (NS - 1);
  float c = cost[pos * DH + d];
  float s = sint[pos * DH + d];
  size_t base = (size_t)tok * ((size_t)nheads * DH) + h * DH + d;
  float x1 = bf2f(buf[base]);
  float x2 = bf2f(buf[base + 128]);
  buf[base] = f2bf(x1 * c - x2 * s);
  buf[base + 128] = f2bf(x2 * c + x1 * s);
}

// ---------------- flash attention (round-6 structure: 1 head/block) --------
// grid: B*NH*(S/64) = 1024; block 256 = 4 waves, each wave 16 q-rows.
// Swapped QK^T: S^T = mfma(K, Q). Fixed-max softmax (softcap bounds |logit|<=50).
// K/V double-buffered via global_load_lds; prefetch t+1 before compute(t);
// ONE __syncthreads per iter.
__global__ __launch_bounds__(256) void attn_kernel(const ushort* __restrict__ q,
                                                   const ushort* __restrict__ k,
                                                   const ushort* __restrict__ vt,
                                                   ushort* __restrict__ ao) {
  __shared__ alignas(16) char lK[2][16384];  // [32 keys][256 d], chunk swz (row&7)
  __shared__ alignas(16) char lV[2][16384];  // [256 d][32 keys], chunk swz ((d>>1)&3)
  const int bid = (int)blockIdx.x;
  const int qb = bid & 31;
  const int h = (bid >> 5) & 15;
  const int b = bid >> 9;
  const int kvh = h >> 1;
  const int qb0 = qb << 6;
  const int t = threadIdx.x;
  const int lane = t & 63;
  const int w = t >> 6;
  const int g = lane >> 4;
  const int lr = lane & 15;

  const int qrow = qb0 + (w << 4) + lr;
  bf16x8_t qf[8];
  const ushort* qbase = q + (size_t)(b * NS + qrow) * (NHEADS * DH) + h * DH;
#pragma unroll
  for (int ks = 0; ks < 8; ++ks)
    qf[ks] = *(const bf16x8_t*)(qbase + (ks << 5) + (g << 3));

  float l_r = 0.f;
  f32x4_t oacc[16] = {};

  const int qminw = qb0 + (w << 4);
  const int qmaxw = qminw + 15;
  int t_lo = qb0 - (WIN - 1);
  if (t_lo < 0) t_lo = 0;
  t_lo &= ~31;
  const int t_hi = qb0 + 63;

  const ushort* kgb = k + (size_t)(b * NS) * (NKVH * DH) + kvh * DH;
  const ushort* vgb = vt + (size_t)((b * NKVH + kvh) * DH) * NS;

  auto stage = [&](int kt, int bi) {
    char* dk = lK[bi];
    char* dv = lV[bi];
#pragma unroll
    for (int j = 0; j < 4; ++j) {
      int row = (w << 3) + (j << 1) + (lane >> 5);
      int ck = (lane & 31) ^ (row & 7);
      gload16(kgb + (size_t)(kt + row) * (NKVH * DH) + (ck << 3),
              dk + (((w << 3) + (j << 1)) << 9));
      int dl = (w << 6) + (j << 4) + (lane >> 2);
      int cv = (lane & 3) ^ ((dl >> 1) & 3);
      gload16(vgb + (size_t)dl * NS + kt + (cv << 3),
              dv + (((w << 2) + j) << 10));
    }
  };

  int cur = 0;
  stage(t_lo, 0);
  __syncthreads();

  for (int kt = t_lo; kt <= t_hi; kt += 32) {
    if (kt + 32 <= t_hi) stage(kt + 32, cur ^ 1);  // async prefetch
    const char* lk = lK[cur];
    const char* lv = lV[cur];
#pragma unroll
    for (int sub = 0; sub < 2; ++sub) {
      const int key0 = kt + (sub << 4);
      if (key0 > qmaxw) continue;
      if (key0 + 15 < qminw - (WIN - 1)) continue;

      f32x4_t sacc = {};
      __builtin_amdgcn_s_setprio(1);
#pragma unroll
      for (int ks = 0; ks < 8; ++ks) {
        int row = (sub << 4) + lr;
        bf16x8_t kf = *(const bf16x8_t*)(lk + (((row << 9) + (ks << 6) + (g << 4)) ^ ((row & 7) << 4)));
        sacc = __builtin_amdgcn_mfma_f32_16x16x32_bf16(kf, qf[ks], sacc, 0, 0, 0);
      }
      __builtin_amdgcn_s_setprio(0);

      float pvv[4];
      const bool full = (key0 + 15 <= qminw) && (key0 >= qmaxw - (WIN - 1));
      if (full) {  // wave-uniform interior: no mask VALU
#pragma unroll
        for (int r = 0; r < 4; ++r) { pvv[r] = pexp(sacc[r]); l_r += pvv[r]; }
      } else {
#pragma unroll
        for (int r = 0; r < 4; ++r) {
          int key = key0 + (g << 2) + r;
          bool ok = (key <= qrow) && (qrow - key < WIN);
          pvv[r] = ok ? pexp(sacc[r]) : 0.f;
          l_r += pvv[r];
        }
      }

      s16x4_t pa;
      pa[0] = (short)f2bf(pvv[0]);
      pa[1] = (short)f2bf(pvv[1]);
      pa[2] = (short)f2bf(pvv[2]);
      pa[3] = (short)f2bf(pvv[3]);

      const int kb2 = (sub << 5) + (g << 3);
      __builtin_amdgcn_s_setprio(1);
#pragma unroll
      for (int dt = 0; dt < 16; ++dt) {
        int d = (dt << 4) + lr;
        s16x4_t vf = *(const s16x4_t*)(lv + ((d << 6) + (kb2 ^ (((d >> 1) & 3) << 4))));
        oacc[dt] = mfma_pv(pa, vf, oacc[dt]);
      }
      __builtin_amdgcn_s_setprio(0);
    }
    __syncthreads();
    cur ^= 1;
  }

  l_r += __shfl_xor(l_r, 16);
  l_r += __shfl_xor(l_r, 32);
  float dn[4];
#pragma unroll
  for (int r = 0; r < 4; ++r)
    dn[r] = 1.0f / __shfl(l_r, (g << 2) + r);

  const int orow0 = b * NS + qb0 + (w << 4) + (g << 2);
#pragma unroll
  for (int dt = 0; dt < 16; ++dt) {
    int col = h * DH + (dt << 4) + lr;
#pragma unroll
    for (int r = 0; r < 4; ++r) {
      ao[(size_t)(orow0 + r) * (NHEADS * DH) + col] = f2bf(oacc[dt][r] * dn[r]);
    }
  }
}

extern "C" void kernel_launch(void* const* d_in, const int* in_sizes, int n_in,
                              void* d_out, int out_size, void* d_ws, size_t ws_size,
                              hipStream_t stream) {
  const float* hs   = (const float*)d_in[0];
  const float* sint = (const float*)d_in[3];
  const float* cost = (const float*)d_in[4];
  const float* Wq = (const float*)d_in[6];
  const float* Wk = (const float*)d_in[7];
  const float* Wv = (const float*)d_in[8];
  const float* Wo = (const float*)d_in[9];

  char* ws = (char*)d_ws;
  size_t off = 0;
  auto alloc = [&](size_t bytes) {
    char* p = ws + off;
    off += (bytes + 255) & ~(size_t)255;
    return p;
  };
  ushort* hsb   = (ushort*)alloc((size_t)4096 * 3584 * 2);  // hs in bf16
  ushort* wT    = (ushort*)alloc((size_t)4096 * 3584 * 2);  // reused weight^T buffer
  ushort* qbuf  = (ushort*)alloc((size_t)4096 * 4096 * 2);
  ushort* kbuf  = (ushort*)alloc((size_t)4096 * 2048 * 2);  // MUST precede vtbuf
  ushort* vtbuf = (ushort*)alloc((size_t)4096 * 2048 * 2);  // = kbuf + 4096*2048
  ushort* aobuf = qbuf;  // alias: attn writes exactly the region only it reads
  if (off > ws_size) return;

  // hs f32 -> bf16
  f32_to_bf16_kernel<<<(4096 * 3584 / 4) / 256, 256, 0, stream>>>(hs, hsb, 4096 * 3584 / 4);

  // fused K+V projection: Bt = [WkT; WvT] stacked in wT
  transpose_f32_bf16<<<(3584 / 64) * (2048 / 64), 256, 0, stream>>>(Wk, wT, 3584, 2048);
  transpose_f32_bf16<<<(3584 / 64) * (2048 / 64), 256, 0, stream>>>(Wv, wT + (size_t)2048 * 3584, 3584, 2048);
  gemm256<4><<<16 * 16, 512, 0, stream>>>(hsb, wT, kbuf, 4096, 4096, 3584);

  // Q projection
  transpose_f32_bf16<<<(3584 / 64) * (4096 / 64), 256, 0, stream>>>(Wq, wT, 3584, 4096);
  gemm256<0><<<16 * 16, 512, 0, stream>>>(hsb, wT, qbuf, 4096, 4096, 3584);

  // RoPE (q then k), in-place
  rope_kernel<<<(4096 * 16 * 128) / 256, 256, 0, stream>>>(qbuf, sint, cost, 16);
  rope_kernel<<<(4096 * 8 * 128) / 256, 256, 0, stream>>>(kbuf, sint, cost, 8);

  // attention: 1 head/block (ao aliases qbuf)
  attn_kernel<<<NB * NHEADS * (NS / 64), 256, 0, stream>>>(qbuf, kbuf, vtbuf, aobuf);

  // output projection, f32 out
  transpose_f32_bf16<<<(4096 / 64) * (3584 / 64), 256, 0, stream>>>(Wo, wT, 4096, 3584);
  gemm256<2><<<16 * 14, 512, 0, stream>>>(aobuf, wT, d_out, 4096, 3584, 4096);
}